// Round 15
// baseline (431.999 us; speedup 1.0000x reference)
//
#include <hip/hip_runtime.h>

#define BOUND 1e-6f
#define HALF_PI 1.57079632679489662f
#define LOG2E 1.44269504088896341f

typedef float f32x4 __attribute__((ext_vector_type(4)));  // clang-native vec4

// DPP helper: masked/out-of-range lanes receive `oldv` (1.0 = mult identity).
#define UPD_DPP(oldv, srcv, ctrl, rmask)                                        \
  __int_as_float(__builtin_amdgcn_update_dpp(                                   \
      __float_as_int(oldv), __float_as_int(srcv), (ctrl), (rmask), 0xF, false))

// Inclusive multiplicative scan across 64 lanes, pure VALU (validated R2-R14).
__device__ __forceinline__ float wave_incl_prod(float x) {
    x *= UPD_DPP(1.0f, x, 0x111, 0xF);  // row_shr:1
    x *= UPD_DPP(1.0f, x, 0x112, 0xF);  // row_shr:2
    x *= UPD_DPP(1.0f, x, 0x114, 0xF);  // row_shr:4
    x *= UPD_DPP(1.0f, x, 0x118, 0xF);  // row_shr:8
    x *= UPD_DPP(1.0f, x, 0x142, 0xA);  // row_bcast:15 -> rows 1,3
    x *= UPD_DPP(1.0f, x, 0x143, 0xC);  // row_bcast:31 -> rows 2,3
    return x;
}

// R15: WAVE-AUTONOMOUS sector-exact blocks, no barrier (de-phasing probe).
// 1-wave (64-thread) blocks, each owning 16 consecutive rows = 16448 B =
// exactly 257 x 64B sectors (minimum sector-exact grain: 257 = 1 mod 16).
// Load all 16 rows up front (16 nt float4 instrs = 16KB in flight), compute
// into a private LDS region, wave-local lgkmcnt(0) (NO s_barrier anywhere),
// then one immediate 17-instr nt burst store of the whole region. With no
// intra-block barrier and 9 independent waves/CU, block lifecycles de-phase
// naturally -> continuous chip-wide memory demand, vs the block-coop
// structure whose ~16 lockstep generations alternate memory bursts with
// compute lulls (the hypothesized last ~9% vs the 6.29 TB/s copy ceiling).
// Per-row math identical to R9/R14.
// out[j]   = radius * prod_{i<j}(sin(a_i)+B) * (cos(a_j)+B),  j < 256
// out[256] = radius * prod_{i<256}(sin(a_i)+B)
__global__ __launch_bounds__(64) void spherize_kernel(
    const float* __restrict__ x,
    const float* __restrict__ p_phiL,
    const float* __restrict__ p_radius,
    const float* __restrict__ p_scaling,
    float* __restrict__ out,
    int n_rows)
{
    __shared__ float lds[16 * 257];   // 16448 B, owned by the single wave

    const float phi_L  = p_phiL[0];
    const float radius = p_radius[0];
    const float cexp   = p_scaling[0] * LOG2E;  // exp(s*x) = exp2(cexp*x)
    const float amp    = HALF_PI - phi_L;

    const int lane = threadIdx.x & 63;
    const int row0 = blockIdx.x * 16;
    const int nr   = min(16, n_rows - row0);

    // ---- load ALL 16 rows up front (16 x nt float4 = 16KB in flight) ----
    f32x4 xv[16];
    const f32x4* xb =
        reinterpret_cast<const f32x4*>(x + (size_t)row0 * 256 + lane * 4);
    #pragma unroll
    for (int i = 0; i < 16; ++i)
        if (i < nr) xv[i] = __builtin_nontemporal_load(xb + i * 64);

    // ---- compute 16 rows into LDS (R9/R14-validated math) ----
    #pragma unroll
    for (int i = 0; i < 16; ++i) {
        if (i >= nr) break;
        float s[4], c[4];
        #pragma unroll
        for (int k = 0; k < 4; ++k) {
            // u = pi/2 - a = amp / (1 + exp(s*x))
            float e  = __builtin_amdgcn_exp2f(cexp * xv[i][k]);
            float u  = amp * __builtin_amdgcn_rcpf(1.0f + e);
            float u2 = u * u;
            s[k] = fmaf(u2, fmaf(u2, 4.16666667e-2f, -0.5f), 1.0f + BOUND);
            float p = fmaf(u2, fmaf(u2, 8.33333333e-3f, -1.66666667e-1f), 1.0f);
            c[k] = fmaf(u, p, BOUND);
        }

        // intra-lane prefix products (exclusive prefixes q* come free)
        float q1 = s[0];
        float q2 = q1 * s[1];
        float q3 = q2 * s[2];
        float t  = q3 * s[3];
        float scan = wave_incl_prod(t);               // inclusive over lanes
        float excl = UPD_DPP(1.0f, scan, 0x138, 0xF); // wave_shr:1, lane0=1.0
        float base = radius * excl;

        float* lrow = lds + i * 257 + lane * 4;
        lrow[0] = base * c[0];
        lrow[1] = base * q1 * c[1];
        lrow[2] = base * q2 * c[2];
        lrow[3] = base * q3 * c[3];
        if (lane == 63)
            lrow[4] = radius * scan;                  // col 256: full product
    }

    // wave-local LDS visibility; NO s_barrier, no vmcnt drain
    asm volatile("s_waitcnt lgkmcnt(0)" ::: "memory");

    // ---- immediate sector-exact nt burst store (17 instrs, 16448 B) ----
    float* obase = out + (size_t)row0 * 257;
    if (nr == 16) {
        // 16*257 = 4112 dwords = 1028 float4; region = 257 full 64B sectors
        const f32x4* l4 = reinterpret_cast<const f32x4*>(lds);
        f32x4*       o4 = reinterpret_cast<f32x4*>(obase);
        #pragma unroll
        for (int j = 0; j < 16; ++j)
            __builtin_nontemporal_store(l4[j * 64 + lane], o4 + j * 64 + lane);
        if (lane < 4)
            __builtin_nontemporal_store(l4[1024 + lane], o4 + 1024 + lane);
    } else {
        // tail block (not hit for N=524288): safe dword cooperative store
        const int nd = nr * 257;
        for (int i = lane; i < nd; i += 64) obase[i] = lds[i];
    }
}

extern "C" void kernel_launch(void* const* d_in, const int* in_sizes, int n_in,
                              void* d_out, int out_size, void* d_ws, size_t ws_size,
                              hipStream_t stream) {
    // inputs: 0=x [N,256], 1=W_theta, 2=W_phi, 3=b_phi, 4=phi_L, 5=radius, 6=scaling
    const float* x         = (const float*)d_in[0];
    const float* p_phiL    = (const float*)d_in[4];
    const float* p_radius  = (const float*)d_in[5];
    const float* p_scaling = (const float*)d_in[6];
    float* out = (float*)d_out;

    const int n_rows = in_sizes[0] / 256;
    const int blocks = (n_rows + 15) / 16;   // 32768 one-wave blocks

    spherize_kernel<<<blocks, 64, 0, stream>>>(x, p_phiL, p_radius, p_scaling,
                                               out, n_rows);
}

// Round 16
// 192.036 us; speedup vs baseline: 2.2496x; 2.2496x over previous
//
#include <hip/hip_runtime.h>

#define BOUND 1e-6f
#define HALF_PI 1.57079632679489662f
#define LOG2E 1.44269504088896341f

typedef float f32x4 __attribute__((ext_vector_type(4)));  // clang-native vec4

// DPP helper: masked/out-of-range lanes receive `oldv` (1.0 = mult identity).
#define UPD_DPP(oldv, srcv, ctrl, rmask)                                        \
  __int_as_float(__builtin_amdgcn_update_dpp(                                   \
      __float_as_int(oldv), __float_as_int(srcv), (ctrl), (rmask), 0xF, false))

// Inclusive multiplicative scan across 64 lanes, pure VALU (validated R2-R15).
__device__ __forceinline__ float wave_incl_prod(float x) {
    x *= UPD_DPP(1.0f, x, 0x111, 0xF);  // row_shr:1
    x *= UPD_DPP(1.0f, x, 0x112, 0xF);  // row_shr:2
    x *= UPD_DPP(1.0f, x, 0x114, 0xF);  // row_shr:4
    x *= UPD_DPP(1.0f, x, 0x118, 0xF);  // row_shr:8
    x *= UPD_DPP(1.0f, x, 0x142, 0xA);  // row_bcast:15 -> rows 1,3
    x *= UPD_DPP(1.0f, x, 0x143, 0xC);  // row_bcast:31 -> rows 2,3
    return x;
}

// R16 = R14 (187us best) with TWO chunks per block through the SAME LDS
// buffer. R15's counters proved stores must be issued as DENSE block-coop
// bursts (sparse sector writes -> MC line-combining times out -> measured 2x
// write amplification), so the barrier+coop-store structure is mandatory.
// This round halves the per-block lifecycle overhead (birth load-latency,
// death store-drain) per byte moved and de-phases write bursts into compute
// lulls: load A+B regs at birth (8KB/wave in flight) -> compute A -> bar ->
// nt burst-store A (no vmcnt drain) -> bar (WAR on LDS) -> compute B (A's
// stores drain underneath) -> bar -> nt burst-store B. LDS unchanged
// (16448 B -> 8 blocks/CU, full 32-wave occupancy); nt on all global access.
// out[j]   = radius * prod_{i<j}(sin(a_i)+B) * (cos(a_j)+B),  j < 256
// out[256] = radius * prod_{i<256}(sin(a_i)+B)
__global__ __launch_bounds__(256) void spherize_kernel(
    const float* __restrict__ x,
    const float* __restrict__ p_phiL,
    const float* __restrict__ p_radius,
    const float* __restrict__ p_scaling,
    float* __restrict__ out,
    int n_rows)
{
    __shared__ float lds[16 * 257];   // 16448 B (= 257 x 64B sectors exactly)

    const float phi_L  = p_phiL[0];
    const float radius = p_radius[0];
    const float cexp   = p_scaling[0] * LOG2E;  // exp(s*x) = exp2(cexp*x)
    const float amp    = HALF_PI - phi_L;

    const int tid  = threadIdx.x;
    const int lane = tid & 63;
    const int wave = tid >> 6;              // 0..3
    const int row0 = blockIdx.x * 32;       // block's first row (2 chunks x 16)

    // ---- load BOTH chunks' rows for this wave at block birth (nt) ----
    auto LOADW = [&](f32x4 (&r)[4], int wrow) {
        const f32x4* xb =
            reinterpret_cast<const f32x4*>(x + (size_t)wrow * 256 + lane * 4);
        #pragma unroll
        for (int i = 0; i < 4; ++i)
            if (wrow + i < n_rows) r[i] = __builtin_nontemporal_load(xb + i * 64);
    };

    // ---- compute one chunk's 16 rows into LDS (R9/R14-validated math) ----
    auto COMPUTE = [&](const f32x4 (&r)[4], int wrow) {
        const int nr_w = min(4, max(0, n_rows - wrow));
        #pragma unroll
        for (int i = 0; i < 4; ++i) {
            if (i >= nr_w) break;
            float s[4], c[4];
            #pragma unroll
            for (int k = 0; k < 4; ++k) {
                // u = pi/2 - a = amp / (1 + exp(s*x))
                float e  = __builtin_amdgcn_exp2f(cexp * r[i][k]);
                float u  = amp * __builtin_amdgcn_rcpf(1.0f + e);
                float u2 = u * u;
                s[k] = fmaf(u2, fmaf(u2, 4.16666667e-2f, -0.5f), 1.0f + BOUND);
                float p = fmaf(u2, fmaf(u2, 8.33333333e-3f, -1.66666667e-1f), 1.0f);
                c[k] = fmaf(u, p, BOUND);
            }
            float q1 = s[0];
            float q2 = q1 * s[1];
            float q3 = q2 * s[2];
            float t  = q3 * s[3];
            float scan = wave_incl_prod(t);               // inclusive over lanes
            float excl = UPD_DPP(1.0f, scan, 0x138, 0xF); // wave_shr:1, lane0=1
            float base = radius * excl;

            float* lrow = lds + (wave * 4 + i) * 257 + lane * 4;
            lrow[0] = base * c[0];
            lrow[1] = base * q1 * c[1];
            lrow[2] = base * q2 * c[2];
            lrow[3] = base * q3 * c[3];
            if (lane == 63)
                lrow[4] = radius * scan;                  // col 256
        }
    };

    // ---- block-coop dense nt burst store of one chunk's region ----
    auto STOREC = [&](int crow0) {
        const int nrb = min(16, n_rows - crow0);
        float* obase = out + (size_t)crow0 * 257;
        if (nrb == 16) {
            // 16*257 = 4112 dwords = 1028 f32x4; region = 257 full 64B sectors
            const f32x4* l4 = reinterpret_cast<const f32x4*>(lds);
            f32x4*       o4 = reinterpret_cast<f32x4*>(obase);
            __builtin_nontemporal_store(l4[tid],       o4 + tid);
            __builtin_nontemporal_store(l4[tid + 256], o4 + tid + 256);
            __builtin_nontemporal_store(l4[tid + 512], o4 + tid + 512);
            __builtin_nontemporal_store(l4[tid + 768], o4 + tid + 768);
            if (tid < 4)
                __builtin_nontemporal_store(l4[tid + 1024], o4 + tid + 1024);
        } else {
            // tail (not hit for N=524288): safe dword cooperative store
            const int nd = nrb * 257;
            for (int i = tid; i < nd; i += 256) obase[i] = lds[i];
        }
    };

    const int wrowA = row0 + wave * 4;        // chunk A rows for this wave
    const int wrowB = row0 + 16 + wave * 4;   // chunk B rows for this wave

    f32x4 xvA[4], xvB[4];
    LOADW(xvA, wrowA);
    const bool haveB = (row0 + 16) < n_rows;  // block-uniform
    if (haveB) LOADW(xvB, wrowB);

    COMPUTE(xvA, wrowA);
    __syncthreads();                 // LDS writes visible to all waves
    STOREC(row0);                    // dense burst; stores stay in flight
    if (haveB) {
        __syncthreads();             // all waves' LDS read-back done (WAR)
        COMPUTE(xvB, wrowB);         // A's stores drain under this compute
        __syncthreads();
        STOREC(row0 + 16);
    }
}

extern "C" void kernel_launch(void* const* d_in, const int* in_sizes, int n_in,
                              void* d_out, int out_size, void* d_ws, size_t ws_size,
                              hipStream_t stream) {
    // inputs: 0=x [N,256], 1=W_theta, 2=W_phi, 3=b_phi, 4=phi_L, 5=radius, 6=scaling
    const float* x         = (const float*)d_in[0];
    const float* p_phiL    = (const float*)d_in[4];
    const float* p_radius  = (const float*)d_in[5];
    const float* p_scaling = (const float*)d_in[6];
    float* out = (float*)d_out;

    const int n_rows = in_sizes[0] / 256;
    const int blocks = (n_rows + 31) / 32;   // 16384 for N=524288

    spherize_kernel<<<blocks, 256, 0, stream>>>(x, p_phiL, p_radius, p_scaling,
                                                out, n_rows);
}

// Round 17
// 186.529 us; speedup vs baseline: 2.3160x; 1.0295x over previous
//
#include <hip/hip_runtime.h>

#define BOUND 1e-6f
#define HALF_PI 1.57079632679489662f
#define LOG2E 1.44269504088896341f

typedef float f32x4 __attribute__((ext_vector_type(4)));  // clang-native vec4

// DPP helper: masked/out-of-range lanes receive `oldv` (1.0 = mult identity).
#define UPD_DPP(oldv, srcv, ctrl, rmask)                                        \
  __int_as_float(__builtin_amdgcn_update_dpp(                                   \
      __float_as_int(oldv), __float_as_int(srcv), (ctrl), (rmask), 0xF, false))

// Inclusive multiplicative scan across 64 lanes, pure VALU (validated R2-R16).
__device__ __forceinline__ float wave_incl_prod(float x) {
    x *= UPD_DPP(1.0f, x, 0x111, 0xF);  // row_shr:1
    x *= UPD_DPP(1.0f, x, 0x112, 0xF);  // row_shr:2
    x *= UPD_DPP(1.0f, x, 0x114, 0xF);  // row_shr:4
    x *= UPD_DPP(1.0f, x, 0x118, 0xF);  // row_shr:8
    x *= UPD_DPP(1.0f, x, 0x142, 0xA);  // row_bcast:15 -> rows 1,3
    x *= UPD_DPP(1.0f, x, 0x143, 0xC);  // row_bcast:31 -> rows 2,3
    return x;
}

// FINAL (= R14, session best: 187.1 us, 5.75 TB/s, 91% of copy ceiling).
// Structure forced by 16 rounds of falsification:
//  - block-coop DENSE sector-exact nt burst stores (16448 B = 257 x 64B
//    sectors) staged via LDS; violating density or alignment costs up to 2x
//    write amplification (measured R15) or +15% (R4 vs R5);
//  - 16-row/256-thread blocks -> 8 blocks/CU, full 32-wave occupancy;
//  - nt loads+stores free L2 allocate/tag bandwidth (-8.3%, R14);
//  - compute (poly sin/cos in u, exp2 sigmoid, intra-lane prefix + one DPP
//    scan) is off the critical path (R2/R3/R6/R7/R8 all null).
// out[j]   = radius * prod_{i<j}(sin(a_i)+B) * (cos(a_j)+B),  j < 256
// out[256] = radius * prod_{i<256}(sin(a_i)+B)
__global__ __launch_bounds__(256) void spherize_kernel(
    const float* __restrict__ x,
    const float* __restrict__ p_phiL,
    const float* __restrict__ p_radius,
    const float* __restrict__ p_scaling,
    float* __restrict__ out,
    int n_rows)
{
    __shared__ float lds[16 * 257];   // 16448 B

    const float phi_L  = p_phiL[0];
    const float radius = p_radius[0];
    const float cexp   = p_scaling[0] * LOG2E;  // exp(s*x) = exp2(cexp*x)
    const float amp    = HALF_PI - phi_L;

    const int tid  = threadIdx.x;
    const int lane = tid & 63;
    const int wave = tid >> 6;              // 0..3
    const int row0 = blockIdx.x * 16;       // block's first row
    const int wrow = row0 + wave * 4;       // this wave's first row

    const int nr_blk = min(16, n_rows - row0);        // rows in this block
    const int nr_w   = min(4, max(0, n_rows - wrow)); // rows for this wave

    // ---- load this wave's 4 rows up front (nt float4, 1KB/instr) ----
    f32x4 xv[4];
    const f32x4* xb =
        reinterpret_cast<const f32x4*>(x + (size_t)wrow * 256 + lane * 4);
    #pragma unroll
    for (int i = 0; i < 4; ++i)
        if (i < nr_w) xv[i] = __builtin_nontemporal_load(xb + i * 64);

    // ---- compute rows into LDS ----
    #pragma unroll
    for (int i = 0; i < 4; ++i) {
        if (i >= nr_w) break;
        float s[4], c[4];
        #pragma unroll
        for (int k = 0; k < 4; ++k) {
            // u = pi/2 - a = amp / (1 + exp(s*x))
            float e  = __builtin_amdgcn_exp2f(cexp * xv[i][k]);
            float u  = amp * __builtin_amdgcn_rcpf(1.0f + e);
            float u2 = u * u;
            s[k] = fmaf(u2, fmaf(u2, 4.16666667e-2f, -0.5f), 1.0f + BOUND);
            float p = fmaf(u2, fmaf(u2, 8.33333333e-3f, -1.66666667e-1f), 1.0f);
            c[k] = fmaf(u, p, BOUND);
        }

        // intra-lane prefix products (exclusive prefixes q* come free)
        float q1 = s[0];
        float q2 = q1 * s[1];
        float q3 = q2 * s[2];
        float t  = q3 * s[3];
        float scan = wave_incl_prod(t);               // inclusive over lanes
        float excl = UPD_DPP(1.0f, scan, 0x138, 0xF); // wave_shr:1, lane0=1.0
        float base = radius * excl;

        float* lrow = lds + (wave * 4 + i) * 257 + lane * 4;
        lrow[0] = base * c[0];
        lrow[1] = base * q1 * c[1];
        lrow[2] = base * q2 * c[2];
        lrow[3] = base * q3 * c[3];
        if (lane == 63)
            lrow[4] = radius * scan;                  // col 256: full product
    }
    __syncthreads();

    // ---- cooperative sector-exact nt burst store of the block's region ----
    float* obase = out + (size_t)row0 * 257;
    if (nr_blk == 16) {
        // 16*257 = 4112 dwords = 1028 float4; region = 257 full 64B sectors
        const f32x4* l4 = reinterpret_cast<const f32x4*>(lds);
        f32x4*       o4 = reinterpret_cast<f32x4*>(obase);
        __builtin_nontemporal_store(l4[tid],       o4 + tid);
        __builtin_nontemporal_store(l4[tid + 256], o4 + tid + 256);
        __builtin_nontemporal_store(l4[tid + 512], o4 + tid + 512);
        __builtin_nontemporal_store(l4[tid + 768], o4 + tid + 768);
        if (tid < 4)
            __builtin_nontemporal_store(l4[tid + 1024], o4 + tid + 1024);
    } else {
        // tail block (not hit for N=524288): safe dword cooperative store
        const int nd = nr_blk * 257;
        for (int i = tid; i < nd; i += 256) obase[i] = lds[i];
    }
}

extern "C" void kernel_launch(void* const* d_in, const int* in_sizes, int n_in,
                              void* d_out, int out_size, void* d_ws, size_t ws_size,
                              hipStream_t stream) {
    // inputs: 0=x [N,256], 1=W_theta, 2=W_phi, 3=b_phi, 4=phi_L, 5=radius, 6=scaling
    const float* x         = (const float*)d_in[0];
    const float* p_phiL    = (const float*)d_in[4];
    const float* p_radius  = (const float*)d_in[5];
    const float* p_scaling = (const float*)d_in[6];
    float* out = (float*)d_out;

    const int n_rows = in_sizes[0] / 256;
    const int blocks = (n_rows + 15) / 16;   // 32768 for N=524288

    spherize_kernel<<<blocks, 256, 0, stream>>>(x, p_phiL, p_radius, p_scaling,
                                                out, n_rows);
}